// Round 7
// baseline (310.798 us; speedup 1.0000x reference)
//
#include <hip/hip_runtime.h>

// SelfAttention B=4 H=16 L=2048 D=64 fp32 in/out.
// Round 9: ISOLATE. r8 bundled {512-thr role-split, bias-C-init, 8-wave geom}
// and failed (absmax 0.88, distinct from r3's 2.016 -> two separate bugs in
// two separate bundles). This round = r5 (verified, 173us kernel) + ONE
// change: 512-thread blocks with role-split staging. Bias kept as r5's
// verbatim bt-array add (NO C-init). Staging statements are r5's verbatim:
// tid<256 run r5's V-staging code, tid>=256 run r5's K-staging code (same
// addresses, same totals). Grid stays 512 (no r6 staging-doubling): 2
// blocks/CU x 8 waves = 16 waves/CU (2x r5's occupancy).
// Carried (r5-verified): exp2-domain softmax (Q pre-scaled 0.125*log2e),
// mask fma-fold into bt, lsum via ones-column MFMA, XCD swizzle, scalar P
// pack/stores, pack2 V staging, cvt_pk Q/K staging.
// NOT carried: r3 layout bundle, r7 ws prep, r8 bias-C-init.
// LDS 39936 B (Ks 9216 | Vt 10240 | Ps 8w x 1280sh = 20480).

constexpr int kH = 16;
constexpr int kL = 2048;
constexpr int kD = 64;

typedef __attribute__((ext_vector_type(8))) short bf16x8;
typedef __attribute__((ext_vector_type(4))) float f32x4;

constexpr float kQScale = 0.125f * 1.44269504088896340736f;  // 1/sqrt(D)*log2e
constexpr float kL2E    = 1.44269504088896340736f;
constexpr float kNegBig = -1e9f;                              // exp2 -> 0

__device__ __forceinline__ unsigned short f2bf(float f) {
  unsigned u = __float_as_uint(f);
  u += 0x7FFF + ((u >> 16) & 1);          // round-to-nearest-even
  return (unsigned short)(u >> 16);
}
__device__ __forceinline__ unsigned pack2(float a, float b) {
  return (unsigned)f2bf(a) | ((unsigned)f2bf(b) << 16);
}
__device__ __forceinline__ unsigned cvt_pk_bf16(float lo, float hi) {
  unsigned r;
  asm("v_cvt_pk_bf16_f32 %0, %1, %2" : "=v"(r) : "v"(lo), "v"(hi));
  return r;
}
__device__ __forceinline__ float exp2_hw(float x) {
  float r; asm("v_exp_f32 %0, %1" : "=v"(r) : "v"(x)); return r;
}

__global__ __launch_bounds__(512, 4)
void attn_fwd(const float* __restrict__ Qg, const float* __restrict__ Kg,
              const float* __restrict__ Vg, const int* __restrict__ maskg,
              const float* __restrict__ biasg, float* __restrict__ outg) {
  // LDS (bytes): [0,9216) Ks 2 bufs x 32keys x 72sh (144B row)
  //              [9216,19456) Vt 2 bufs x 64d x 40sh (80B row)
  //              [19456,39936) Ps 8 waves x 32q x 40sh
  // Prologue reuses [0,36864) as Qs 256q x 72sh.
  __shared__ __align__(16) char smem[39936];
  unsigned short* const KsBase = (unsigned short*)smem;
  unsigned short* const VtBase = (unsigned short*)(smem + 9216);
  unsigned short* const QsAll  = (unsigned short*)smem;

  const int tid  = threadIdx.x;
  const int lane = tid & 63;
  const int w    = tid >> 6;        // wave 0..7, owns q-rows w*32 .. w*32+31
  const int col  = lane & 15;
  const int quad = lane >> 4;

  // XCD swizzle (r5-verified): 512 blocks, bijective; 16 heads of one (b,qb)
  // bias panel co-reside on one XCD's L2.
  const int wg = blockIdx.x + (blockIdx.y << 4) + (blockIdx.z << 7);
  const int sw = ((wg & 7) << 6) | (wg >> 3);
  const int h  = sw & 15;
  const int qb = (sw >> 4) & 7;
  const int b  = sw >> 7;
  const int q0 = qb * 256;

  unsigned short* const Ps = (unsigned short*)(smem + 19456) + w * 1280;

  const size_t bh = (size_t)b * kH + h;
  const float4* const Q4 = (const float4*)(Qg + (bh * kL + q0) * kD);
  const float4* const K4 = (const float4*)(Kg + bh * kL * kD);
  const float4* const V4 = (const float4*)(Vg + bh * kL * kD);
  const float*  const brow = biasg + (size_t)b * kL * kL;
  const int*    const mrow = maskg + b * kL;

  // ---- prologue: stage Q*(0.125*log2e) fp32->bf16 into Qs, load frags ----
#pragma unroll
  for (int i = 0; i < 8; ++i) {
    const int slot = tid + i * 512;         // 256 rows x 16 float4
    const int row = slot >> 4, dc = slot & 15;
    const float4 v = Q4[slot];
    *(uint2*)&QsAll[row * 72 + dc * 4] =
        make_uint2(cvt_pk_bf16(v.x * kQScale, v.y * kQScale),
                   cvt_pk_bf16(v.z * kQScale, v.w * kQScale));
  }
  __syncthreads();
  bf16x8 qf[2][2];                          // [qtile][d-chunk] persistent
#pragma unroll
  for (int qt = 0; qt < 2; ++qt)
#pragma unroll
    for (int kc = 0; kc < 2; ++kc)
      qf[qt][kc] = *(const bf16x8*)
          &QsAll[(w * 32 + qt * 16 + col) * 72 + kc * 32 + quad * 8];
  __syncthreads();                          // Qs dead; smem now Ks/Vt/Ps

  // staging role split: tid<256 run r5's V-staging, tid>=256 r5's K-staging.
  const int tidK = tid & 255;
  const int keyA = tidK >> 4, dcA = tidK & 15;  // K: keys keyA, keyA+16
  const int jp   = tidK >> 4, dcv = tidK & 15;  // V: key pair (2jp, 2jp+1)
  const bool isV = (tid < 256);

  // ---- stage tile 0 into buf 0 (r5 layouts verbatim) ----
  if (isV) {
    const float4 v0 = V4[(2 * jp) * 16 + dcv];
    const float4 v1 = V4[(2 * jp + 1) * 16 + dcv];
    *(unsigned*)&VtBase[(dcv * 4 + 0) * 40 + 2 * jp] = pack2(v0.x, v1.x);
    *(unsigned*)&VtBase[(dcv * 4 + 1) * 40 + 2 * jp] = pack2(v0.y, v1.y);
    *(unsigned*)&VtBase[(dcv * 4 + 2) * 40 + 2 * jp] = pack2(v0.z, v1.z);
    *(unsigned*)&VtBase[(dcv * 4 + 3) * 40 + 2 * jp] = pack2(v0.w, v1.w);
  } else {
    const float4 a = K4[keyA * 16 + dcA];
    const float4 c = K4[(16 + keyA) * 16 + dcA];
    *(uint2*)&KsBase[keyA * 72 + dcA * 4] =
        make_uint2(cvt_pk_bf16(a.x, a.y), cvt_pk_bf16(a.z, a.w));
    *(uint2*)&KsBase[(keyA + 16) * 72 + dcA * 4] =
        make_uint2(cvt_pk_bf16(c.x, c.y), cvt_pk_bf16(c.z, c.w));
  }

  f32x4 oacc[2][5];                         // [qtile][4 dtiles + lsum]
  const f32x4 z4 = {0.f, 0.f, 0.f, 0.f};
#pragma unroll
  for (int qt = 0; qt < 2; ++qt)
#pragma unroll
    for (int dt = 0; dt < 5; ++dt) oacc[qt][dt] = z4;

  bf16x8 vones;                             // all-ones B frag: row-sum MFMA
#pragma unroll
  for (int i = 0; i < 8; ++i) vones[i] = (short)0x3F80;

  const float* const bb =
      brow + (size_t)(q0 + w * 32 + quad * 4) * kL + col;

  for (int t = 0; t < 64; ++t) {
    const int buf = t & 1;
    const int k0 = t * 32;
    unsigned short* const Ks = KsBase + buf * 2304;
    unsigned short* const Vt = VtBase + buf * 2560;

    // prefetch next tile (role-split; latency hidden by compute)
    float4 pa, pb;
    const bool pf = (t < 63);
    if (pf) {
      const int kn = k0 + 32;
      if (isV) {
        pa = V4[(kn + 2 * jp) * 16 + dcv];
        pb = V4[(kn + 2 * jp + 1) * 16 + dcv];
      } else {
        pa = K4[(kn + keyA) * 16 + dcA];
        pb = K4[(kn + 16 + keyA) * 16 + dcA];
      }
    }

    // bias + mask (r5 verbatim): fold mask & log2e via fma constants
    const int mk0 = mrow[k0 + col];
    const int mk1 = mrow[k0 + 16 + col];
    const float sel0 = mk0 ? kL2E : 0.f, add0 = mk0 ? 0.f : kNegBig;
    const float sel1 = mk1 ? kL2E : 0.f, add1 = mk1 ? 0.f : kNegBig;
    float bt[2][4][2];
#pragma unroll
    for (int qt = 0; qt < 2; ++qt)
#pragma unroll
      for (int r = 0; r < 4; ++r) {
        const float* bp = bb + (size_t)(qt * 16 + r) * kL + k0;
        bt[qt][r][0] = fmaf(bp[0], sel0, add0);
        bt[qt][r][1] = fmaf(bp[16], sel1, add1);
      }

    __syncthreads();                        // staging of tile t complete

    // ---- S = Q K^T (per wave: 32q x 32k), scores in log2 domain ----
    f32x4 sacc[2][2];
#pragma unroll
    for (int qt = 0; qt < 2; ++qt) { sacc[qt][0] = z4; sacc[qt][1] = z4; }
#pragma unroll
    for (int kc = 0; kc < 2; ++kc) {
      const bf16x8 bk0 = *(const bf16x8*)&Ks[col * 72 + kc * 32 + quad * 8];
      const bf16x8 bk1 = *(const bf16x8*)&Ks[(16 + col) * 72 + kc * 32 + quad * 8];
#pragma unroll
      for (int qt = 0; qt < 2; ++qt) {
        sacc[qt][0] = __builtin_amdgcn_mfma_f32_16x16x32_bf16(
            qf[qt][kc], bk0, sacc[qt][0], 0, 0, 0);
        sacc[qt][1] = __builtin_amdgcn_mfma_f32_16x16x32_bf16(
            qf[qt][kc], bk1, sacc[qt][1], 0, 0, 0);
      }
    }

    // ---- p = exp2(s + bias'), write P (bf16) to LDS (r5 verbatim) ----
#pragma unroll
    for (int qt = 0; qt < 2; ++qt)
#pragma unroll
      for (int r = 0; r < 4; ++r) {
        const float p0 = exp2_hw(sacc[qt][0][r] + bt[qt][r][0]);
        const float p1 = exp2_hw(sacc[qt][1][r] + bt[qt][r][1]);
        const int prow = (qt * 16 + quad * 4 + r) * 40;
        Ps[prow + col]      = (unsigned short)((__float_as_uint(p0) + 0x8000) >> 16);
        Ps[prow + 16 + col] = (unsigned short)((__float_as_uint(p1) + 0x8000) >> 16);
      }
    asm volatile("" ::: "memory");          // pin P stores before ap reads

    // ---- O += P V  (+ ones-column MFMA accumulates row sums) ----
    bf16x8 ap[2];
#pragma unroll
    for (int qt = 0; qt < 2; ++qt)
      ap[qt] = *(const bf16x8*)&Ps[(qt * 16 + col) * 40 + quad * 8];
#pragma unroll
    for (int dt = 0; dt < 4; ++dt) {
      const bf16x8 bv = *(const bf16x8*)&Vt[(dt * 16 + col) * 40 + quad * 8];
#pragma unroll
      for (int qt = 0; qt < 2; ++qt)
        oacc[qt][dt] = __builtin_amdgcn_mfma_f32_16x16x32_bf16(
            ap[qt], bv, oacc[qt][dt], 0, 0, 0);
    }
#pragma unroll
    for (int qt = 0; qt < 2; ++qt)
      oacc[qt][4] = __builtin_amdgcn_mfma_f32_16x16x32_bf16(
          ap[qt], vones, oacc[qt][4], 0, 0, 0);

    // ---- write prefetched tile t+1 into the other buffer (r5 layouts) ----
    if (pf) {
      if (isV) {
        unsigned short* const Vtn = VtBase + (buf ^ 1) * 2560;
        *(unsigned*)&Vtn[(dcv * 4 + 0) * 40 + 2 * jp] = pack2(pa.x, pb.x);
        *(unsigned*)&Vtn[(dcv * 4 + 1) * 40 + 2 * jp] = pack2(pa.y, pb.y);
        *(unsigned*)&Vtn[(dcv * 4 + 2) * 40 + 2 * jp] = pack2(pa.z, pb.z);
        *(unsigned*)&Vtn[(dcv * 4 + 3) * 40 + 2 * jp] = pack2(pa.w, pb.w);
      } else {
        unsigned short* const Ksn = KsBase + (buf ^ 1) * 2304;
        *(uint2*)&Ksn[keyA * 72 + dcA * 4] =
            make_uint2(cvt_pk_bf16(pa.x, pa.y), cvt_pk_bf16(pa.z, pa.w));
        *(uint2*)&Ksn[(keyA + 16) * 72 + dcA * 4] =
            make_uint2(cvt_pk_bf16(pb.x, pb.y), cvt_pk_bf16(pb.z, pb.w));
      }
    }
  }

  // ---- epilogue: lsum already in oacc[qt][4][r] for every lane ----
  float* const orow = outg + (bh * kL + q0) * kD;
#pragma unroll
  for (int qt = 0; qt < 2; ++qt)
#pragma unroll
    for (int r = 0; r < 4; ++r) {
      const float li = 1.0f / oacc[qt][4][r];
      float* op = orow + (size_t)(w * 32 + qt * 16 + quad * 4 + r) * kD + col;
#pragma unroll
      for (int dt = 0; dt < 4; ++dt)
        op[dt * 16] = oacc[qt][dt][r] * li;
    }
}

extern "C" void kernel_launch(void* const* d_in, const int* in_sizes, int n_in,
                              void* d_out, int out_size, void* d_ws, size_t ws_size,
                              hipStream_t stream) {
  const float* Q    = (const float*)d_in[0];
  const float* K    = (const float*)d_in[1];
  const float* V    = (const float*)d_in[2];
  const int*   mask = (const int*)d_in[3];
  const float* bias = (const float*)d_in[4];
  float* out = (float*)d_out;

  dim3 grid(kH, kL / 256, 4);   // (16, 8, 4) = 512 blocks = 2/CU
  dim3 block(512);              // 8 waves -> 16 waves/CU
  attn_fwd<<<grid, block, 0, stream>>>(Q, K, V, mask, bias, out);
}

// Round 8
// 283.270 us; speedup vs baseline: 1.0972x; 1.0972x over previous
//
#include <hip/hip_runtime.h>

// SelfAttention B=4 H=16 L=2048 D=64 fp32 in/out.
// Round 10: safe VALU cuts on the r5 base (173us kernel; best verified).
//   r9 lesson: qt=4 geometry wins (every wave reads the whole K/V tile from
//   LDS, so halving qt doubles LDS-read per FLOP; r6/r9 both regressed).
//   Occupancy experiments closed. This round removes VALU only, zero layout
//   or store-type changes:
//   - V staging pack2 -> v_cvt_pk_bf16_f32 (bit-identical RNE for normals,
//     ~10 ops -> 1 op per pair; 4 pairs/thread/tile).
//   - P pack: one cvt_pk + shift yields both b16 halves (was 2x add+shift);
//     stores remain the same unsigned short b16 stores (no TBAA change).
//   - bias row pointers hoisted out of the t-loop (16 per-(qt,r) bases;
//     inner loop = two imm-offset loads each).
// Carried (r5-verified): QT=256/4-wave/qt=4 geometry, exp2-domain softmax,
// mask fma-fold, lsum via ones-column MFMA, XCD swizzle, scalar b16 P stores,
// cvt_pk Q/K staging. Quarantined: r3 layout bundle, bias-C-init, r7 ws prep.
// LDS 39936 B -> 2 blocks/CU (512-block grid).

constexpr int kH = 16;
constexpr int kL = 2048;
constexpr int kD = 64;

typedef __attribute__((ext_vector_type(8))) short bf16x8;
typedef __attribute__((ext_vector_type(4))) float f32x4;

constexpr float kQScale = 0.125f * 1.44269504088896340736f;  // 1/sqrt(D)*log2e
constexpr float kL2E    = 1.44269504088896340736f;
constexpr float kNegBig = -1e9f;                              // exp2 -> 0

__device__ __forceinline__ unsigned cvt_pk_bf16(float lo, float hi) {
  unsigned r;
  asm("v_cvt_pk_bf16_f32 %0, %1, %2" : "=v"(r) : "v"(lo), "v"(hi));
  return r;
}
__device__ __forceinline__ float exp2_hw(float x) {
  float r; asm("v_exp_f32 %0, %1" : "=v"(r) : "v"(x)); return r;
}

__global__ __launch_bounds__(256, 2)
void attn_fwd(const float* __restrict__ Qg, const float* __restrict__ Kg,
              const float* __restrict__ Vg, const int* __restrict__ maskg,
              const float* __restrict__ biasg, float* __restrict__ outg) {
  // LDS layout (bytes): [0,9216) Ks 2 bufs x 32keys x 72 bf16 (stride 144B)
  //                     [9216,19456) Vt 2 bufs x 64d x 40 bf16 (stride 80B)
  //                     [19456,39936) Ps 4 waves x 64q x 40 bf16
  // Prologue reuses [0,36864) as Qs 256q x 72 bf16.
  __shared__ __align__(16) char smem[39936];
  unsigned short* const KsBase = (unsigned short*)smem;
  unsigned short* const VtBase = (unsigned short*)(smem + 9216);
  unsigned short* const QsAll  = (unsigned short*)smem;

  const int tid  = threadIdx.x;
  const int lane = tid & 63;
  const int w    = tid >> 6;        // wave 0..3, owns q-rows w*64 .. w*64+63
  const int col  = lane & 15;
  const int quad = lane >> 4;

  // XCD swizzle (r5-verified): 512 blocks, bijective; 16 heads of one (b,qb)
  // bias panel co-reside on one XCD's L2.
  const int wg = blockIdx.x + (blockIdx.y << 4) + (blockIdx.z << 7);
  const int sw = ((wg & 7) << 6) | (wg >> 3);
  const int h  = sw & 15;
  const int qb = (sw >> 4) & 7;
  const int b  = sw >> 7;
  const int q0 = qb * 256;

  unsigned short* const Ps = (unsigned short*)(smem + 19456) + w * 2560;

  const size_t bh = (size_t)b * kH + h;
  const float4* const Q4 = (const float4*)(Qg + (bh * kL + q0) * kD);
  const float4* const K4 = (const float4*)(Kg + bh * kL * kD);
  const float4* const V4 = (const float4*)(Vg + bh * kL * kD);
  const float*  const brow = biasg + (size_t)b * kL * kL;
  const int*    const mrow = maskg + b * kL;

  // ---- prologue: stage Q*(0.125*log2e) fp32->bf16 into Qs, load frags ----
#pragma unroll
  for (int i = 0; i < 16; ++i) {
    const int slot = tid + i * 256;         // 256 rows x 16 float4
    const int row = slot >> 4, dc = slot & 15;
    const float4 v = Q4[slot];
    *(uint2*)&QsAll[row * 72 + dc * 4] =
        make_uint2(cvt_pk_bf16(v.x * kQScale, v.y * kQScale),
                   cvt_pk_bf16(v.z * kQScale, v.w * kQScale));
  }
  __syncthreads();
  bf16x8 qf[4][2];                          // [qtile][d-chunk] persistent
#pragma unroll
  for (int qt = 0; qt < 4; ++qt)
#pragma unroll
    for (int kc = 0; kc < 2; ++kc)
      qf[qt][kc] = *(const bf16x8*)
          &QsAll[(w * 64 + qt * 16 + col) * 72 + kc * 32 + quad * 8];
  __syncthreads();                          // Qs dead; smem now Ks/Vt/Ps

  // staging index split (coalesced 256B row reads)
  const int keyA = tid >> 4, dcA = tid & 15;   // K: keys keyA, keyA+16
  const int jp   = tid >> 4, dcv = tid & 15;   // V: key pair (2jp, 2jp+1)

  // ---- stage tile 0 into buf 0 (r5 layouts; cvt_pk values, RNE) ----
  {
    const float4 a  = K4[keyA * 16 + dcA];
    const float4 c  = K4[(16 + keyA) * 16 + dcA];
    const float4 v0 = V4[(2 * jp) * 16 + dcv];
    const float4 v1 = V4[(2 * jp + 1) * 16 + dcv];
    *(uint2*)&KsBase[keyA * 72 + dcA * 4] =
        make_uint2(cvt_pk_bf16(a.x, a.y), cvt_pk_bf16(a.z, a.w));
    *(uint2*)&KsBase[(keyA + 16) * 72 + dcA * 4] =
        make_uint2(cvt_pk_bf16(c.x, c.y), cvt_pk_bf16(c.z, c.w));
    *(unsigned*)&VtBase[(dcv * 4 + 0) * 40 + 2 * jp] = cvt_pk_bf16(v0.x, v1.x);
    *(unsigned*)&VtBase[(dcv * 4 + 1) * 40 + 2 * jp] = cvt_pk_bf16(v0.y, v1.y);
    *(unsigned*)&VtBase[(dcv * 4 + 2) * 40 + 2 * jp] = cvt_pk_bf16(v0.z, v1.z);
    *(unsigned*)&VtBase[(dcv * 4 + 3) * 40 + 2 * jp] = cvt_pk_bf16(v0.w, v1.w);
  }

  f32x4 oacc[4][5];                         // [qtile][4 dtiles + lsum]
  const f32x4 z4 = {0.f, 0.f, 0.f, 0.f};
#pragma unroll
  for (int qt = 0; qt < 4; ++qt)
#pragma unroll
    for (int dt = 0; dt < 5; ++dt) oacc[qt][dt] = z4;

  bf16x8 vones;                             // all-ones B frag: row-sum MFMA
#pragma unroll
  for (int i = 0; i < 8; ++i) vones[i] = (short)0x3F80;

  // bias row pointers hoisted out of the t-loop (inner = imm-offset loads)
  const float* const bb =
      brow + (size_t)(q0 + w * 64 + quad * 4) * kL + col;
  const float* bq[4][4];
#pragma unroll
  for (int qt = 0; qt < 4; ++qt)
#pragma unroll
    for (int r = 0; r < 4; ++r)
      bq[qt][r] = bb + (size_t)(qt * 16 + r) * kL;

  for (int t = 0; t < 64; ++t) {
    const int buf = t & 1;
    const int k0 = t * 32;
    unsigned short* const Ks = KsBase + buf * 2304;
    unsigned short* const Vt = VtBase + buf * 2560;

    // prefetch next K/V tile into registers (latency hidden by compute)
    float4 pk0, pk1, pv0, pv1;
    const bool pf = (t < 63);
    if (pf) {
      const int kn = k0 + 32;
      pk0 = K4[(kn + keyA) * 16 + dcA];
      pk1 = K4[(kn + 16 + keyA) * 16 + dcA];
      pv0 = V4[(kn + 2 * jp) * 16 + dcv];
      pv1 = V4[(kn + 2 * jp + 1) * 16 + dcv];
    }

    // bias + mask (r5 verbatim): fold mask & log2e via fma constants
    const int mk0 = mrow[k0 + col];
    const int mk1 = mrow[k0 + 16 + col];
    const float sel0 = mk0 ? kL2E : 0.f, add0 = mk0 ? 0.f : kNegBig;
    const float sel1 = mk1 ? kL2E : 0.f, add1 = mk1 ? 0.f : kNegBig;
    float bt[4][4][2];
#pragma unroll
    for (int qt = 0; qt < 4; ++qt)
#pragma unroll
      for (int r = 0; r < 4; ++r) {
        const float* bp = bq[qt][r] + k0;
        bt[qt][r][0] = fmaf(bp[0], sel0, add0);
        bt[qt][r][1] = fmaf(bp[16], sel1, add1);
      }

    __syncthreads();                        // staging of tile t complete

    // ---- S = Q K^T (per wave: 64q x 32k), scores in log2 domain ----
    f32x4 sacc[4][2];
#pragma unroll
    for (int qt = 0; qt < 4; ++qt) { sacc[qt][0] = z4; sacc[qt][1] = z4; }
#pragma unroll
    for (int kc = 0; kc < 2; ++kc) {
      const bf16x8 bk0 = *(const bf16x8*)&Ks[col * 72 + kc * 32 + quad * 8];
      const bf16x8 bk1 = *(const bf16x8*)&Ks[(16 + col) * 72 + kc * 32 + quad * 8];
#pragma unroll
      for (int qt = 0; qt < 4; ++qt) {
        sacc[qt][0] = __builtin_amdgcn_mfma_f32_16x16x32_bf16(
            qf[qt][kc], bk0, sacc[qt][0], 0, 0, 0);
        sacc[qt][1] = __builtin_amdgcn_mfma_f32_16x16x32_bf16(
            qf[qt][kc], bk1, sacc[qt][1], 0, 0, 0);
      }
    }

    // ---- p = exp2(s + bias'), P pack via cvt_pk (RNE), b16 stores (r5) ----
#pragma unroll
    for (int qt = 0; qt < 4; ++qt)
#pragma unroll
      for (int r = 0; r < 4; ++r) {
        const float p0 = exp2_hw(sacc[qt][0][r] + bt[qt][r][0]);
        const float p1 = exp2_hw(sacc[qt][1][r] + bt[qt][r][1]);
        const unsigned pp = cvt_pk_bf16(p0, p1);
        const int prow = (qt * 16 + quad * 4 + r) * 40;
        Ps[prow + col]      = (unsigned short)pp;
        Ps[prow + 16 + col] = (unsigned short)(pp >> 16);
      }
    asm volatile("" ::: "memory");          // pin P stores before ap reads

    // ---- O += P V  (+ ones-column MFMA accumulates row sums) ----
    bf16x8 ap[4];
#pragma unroll
    for (int qt = 0; qt < 4; ++qt)
      ap[qt] = *(const bf16x8*)&Ps[(qt * 16 + col) * 40 + quad * 8];
#pragma unroll
    for (int dt = 0; dt < 4; ++dt) {
      const bf16x8 bv = *(const bf16x8*)&Vt[(dt * 16 + col) * 40 + quad * 8];
#pragma unroll
      for (int qt = 0; qt < 4; ++qt)
        oacc[qt][dt] = __builtin_amdgcn_mfma_f32_16x16x32_bf16(
            ap[qt], bv, oacc[qt][dt], 0, 0, 0);
    }
#pragma unroll
    for (int qt = 0; qt < 4; ++qt)
      oacc[qt][4] = __builtin_amdgcn_mfma_f32_16x16x32_bf16(
          ap[qt], vones, oacc[qt][4], 0, 0, 0);

    // ---- write prefetched tile t+1 into the other buffer (r5 layouts) ----
    if (pf) {
      unsigned short* const Ksn = KsBase + (buf ^ 1) * 2304;
      unsigned short* const Vtn = VtBase + (buf ^ 1) * 2560;
      *(uint2*)&Ksn[keyA * 72 + dcA * 4] =
          make_uint2(cvt_pk_bf16(pk0.x, pk0.y), cvt_pk_bf16(pk0.z, pk0.w));
      *(uint2*)&Ksn[(keyA + 16) * 72 + dcA * 4] =
          make_uint2(cvt_pk_bf16(pk1.x, pk1.y), cvt_pk_bf16(pk1.z, pk1.w));
      *(unsigned*)&Vtn[(dcv * 4 + 0) * 40 + 2 * jp] = cvt_pk_bf16(pv0.x, pv1.x);
      *(unsigned*)&Vtn[(dcv * 4 + 1) * 40 + 2 * jp] = cvt_pk_bf16(pv0.y, pv1.y);
      *(unsigned*)&Vtn[(dcv * 4 + 2) * 40 + 2 * jp] = cvt_pk_bf16(pv0.z, pv1.z);
      *(unsigned*)&Vtn[(dcv * 4 + 3) * 40 + 2 * jp] = cvt_pk_bf16(pv0.w, pv1.w);
    }
  }

  // ---- epilogue: lsum already in oacc[qt][4][r] for every lane ----
  float* const orow = outg + (bh * kL + q0) * kD;
#pragma unroll
  for (int qt = 0; qt < 4; ++qt)
#pragma unroll
    for (int r = 0; r < 4; ++r) {
      const float li = 1.0f / oacc[qt][4][r];
      float* op = orow + (size_t)(w * 64 + qt * 16 + quad * 4 + r) * kD + col;
#pragma unroll
      for (int dt = 0; dt < 4; ++dt)
        op[dt * 16] = oacc[qt][dt][r] * li;
    }
}

extern "C" void kernel_launch(void* const* d_in, const int* in_sizes, int n_in,
                              void* d_out, int out_size, void* d_ws, size_t ws_size,
                              hipStream_t stream) {
  const float* Q    = (const float*)d_in[0];
  const float* K    = (const float*)d_in[1];
  const float* V    = (const float*)d_in[2];
  const int*   mask = (const int*)d_in[3];
  const float* bias = (const float*)d_in[4];
  float* out = (float*)d_out;

  dim3 grid(kH, kL / 256, 4);   // (16, 8, 4) = 512 blocks = 2/CU
  dim3 block(256);
  attn_fwd<<<grid, block, 0, stream>>>(Q, K, V, mask, bias, out);
}